// Round 22
// baseline (444.398 us; speedup 1.0000x reference)
//
#include <hip/hip_runtime.h>
#include <hip/hip_bf16.h>
#include <cstdint>

// LeViT attention block: LN -> QKV gemm -> biased attention -> proj gemm
// B=128, N=196, DIM=576, H=18, KD=32, DV=128, DH=2304, QKVO=3456
// fp32 in/out; internal compute bf16 MFMA + fp32 accum.
// ws: qkv(173.4M) + wq(4M) + wp(3M) + bias_t(3.1M) = 183.5 MB.
// xn staged in d_out (dead before proj gemm). Attn output overwrites the
// V slot of qkv in place. Bias pre-scaled by log2(e) (exp2-domain softmax).
// GEMM: 256x128 tile, 512 thr (8 waves, 4Mx2N), BK=32, TRIPLE-buffered
// 72 KB LDS at stage-distance 2, ONE barrier per K-step, counted vmcnt(3),
// LDS-staged coalesced C epilogue + T5 setprio.
// R21/22: A-staging loads NON-TEMPORAL (aux=2) + C stores nontemporal
// (ext-vector types only — HIP float4 class rejected by the builtin).
// R20 showed FETCH 168MB vs 33MB ideal: streaming A + C evict L2-resident
// B (wq=4MB = one XCD L2). NT keeps B resident.
// Attn: 448 thr / 7 waves, tiles {w,w+7} interleaved (2x ILP); V in
// conflict-free 16B-chunk layout; NO-MAX softmax; prep+LN fused.

typedef uint32_t u32;
typedef unsigned short u16;
using f32x4 = __attribute__((ext_vector_type(4))) float;
using s16x8 = __attribute__((ext_vector_type(8))) short;

#define DEVFN static __device__ __forceinline__

DEVFN u16 f2bf(float f) {  // RNE float->bf16
  u32 u = __builtin_bit_cast(u32, f);
  u = (u + 0x7fffu + ((u >> 16) & 1u)) >> 16;
  return (u16)u;
}

DEVFN u32 cvtpk_bf16(float lo, float hi) {  // packed RNE pair
  u32 r;
  asm("v_cvt_pk_bf16_f32 %0, %1, %2" : "=v"(r) : "v"(lo), "v"(hi));
  return r;
}

DEVFN float exp2_fast(float x) {
  float r;
  asm("v_exp_f32 %0, %1" : "=v"(r) : "v"(x));
  return r;
}

DEVFN void gload_lds16(const void* g, void* l) {
  typedef const __attribute__((address_space(1))) uint32_t* gp_t;
  typedef __attribute__((address_space(3))) uint32_t* lp_t;
  __builtin_amdgcn_global_load_lds((gp_t)g, (lp_t)l, 16, 0, 0);
}

DEVFN void gload_lds16_nt(const void* g, void* l) {  // non-temporal (CPol NT=2)
  typedef const __attribute__((address_space(1))) uint32_t* gp_t;
  typedef __attribute__((address_space(3))) uint32_t* lp_t;
  __builtin_amdgcn_global_load_lds((gp_t)g, (lp_t)l, 16, 0, 2);
}

// ---------------- fused LN + prep (cvt wq, cvt_pad wp, bias table) ----------------
// blocks 0..6271: LayerNorm (4 tokens/block); 6272..: prep work.
__launch_bounds__(256)
__global__ void k_prep_ln(const float* __restrict__ x, const float* __restrict__ ln_g,
                          const float* __restrict__ ln_b, u16* __restrict__ xn,
                          const float* __restrict__ qkv_w, const float* __restrict__ proj_w,
                          const float* __restrict__ biases, const int* __restrict__ idxs,
                          u16* __restrict__ wq, u16* __restrict__ wp,
                          float* __restrict__ bfull, int noff) {
  int bid = blockIdx.x;
  if (bid < 6272) {
    int t = bid * 4 + (threadIdx.x >> 6);
    int l = threadIdx.x & 63;
    const float* xt = x + (size_t)t * 576;
    const float4* x4 = (const float4*)xt;
    float4 v0 = x4[l], v1 = x4[64 + l];
    float v2 = xt[512 + l];
    float s = v0.x + v0.y + v0.z + v0.w + v1.x + v1.y + v1.z + v1.w + v2;
    float q = v0.x * v0.x + v0.y * v0.y + v0.z * v0.z + v0.w * v0.w +
              v1.x * v1.x + v1.y * v1.y + v1.z * v1.z + v1.w * v1.w + v2 * v2;
    for (int o = 1; o < 64; o <<= 1) {
      s += __shfl_xor(s, o, 64);
      q += __shfl_xor(q, o, 64);
    }
    float mean = s * (1.f / 576.f);
    float var = q * (1.f / 576.f) - mean * mean;
    float rstd = rsqrtf(var + 1e-5f);
    const float4* g4 = (const float4*)ln_g;
    const float4* b4 = (const float4*)ln_b;
    float4 ga = g4[l], gb = g4[64 + l];
    float4 ba = b4[l], bb = b4[64 + l];
    float gc = ln_g[512 + l], bc = ln_b[512 + l];
    u16* ot = xn + (size_t)t * 576;
    ushort4 o0, o1;
    o0.x = f2bf((v0.x - mean) * rstd * ga.x + ba.x);
    o0.y = f2bf((v0.y - mean) * rstd * ga.y + ba.y);
    o0.z = f2bf((v0.z - mean) * rstd * ga.z + ba.z);
    o0.w = f2bf((v0.w - mean) * rstd * ga.w + ba.w);
    o1.x = f2bf((v1.x - mean) * rstd * gb.x + bb.x);
    o1.y = f2bf((v1.y - mean) * rstd * gb.y + bb.y);
    o1.z = f2bf((v1.z - mean) * rstd * gb.z + bb.z);
    o1.w = f2bf((v1.w - mean) * rstd * gb.w + bb.w);
    ((ushort4*)ot)[l] = o0;
    ((ushort4*)ot)[64 + l] = o1;
    ot[512 + l] = f2bf((v2 - mean) * rstd * gc + bc);
  } else if (bid < 6272 + 7776) {
    int i = (bid - 6272) * 256 + threadIdx.x;
    if (i < 1990656) wq[i] = f2bf(qkv_w[i]);
  } else if (bid < 6272 + 7776 + 5760) {
    int i = (bid - 6272 - 7776) * 256 + threadIdx.x;  // over 640*2304
    int r = i / 2304, c = i % 2304;
    wp[i] = (r < 576) ? f2bf(proj_w[r * 2304 + c]) : (u16)0;
  } else {
    int i = (bid - 6272 - 7776 - 5760) * 256 + threadIdx.x;  // over 18*13*13*256
    int r = i & 3, g = (i >> 2) & 3, q16 = (i >> 4) & 15;
    int t = i >> 8;
    int mt = t % 13, t2 = t / 13;
    int qt = t2 % 13, h = t2 / 13;
    int q = qt * 16 + q16, m = mt * 16 + g * 4 + r;
    float v = -1e30f;
    if (q < 196 && m < 196)
      v = biases[h * noff + idxs[q * 196 + m]] * 1.4426950408889634f;
    bfull[i] = v;
  }
}

// ---------------- GEMM: C[M,nvalid] = A[M,K] * Bt[N,K]^T + bias ----------------
// 256x128 tile, BK=32, 8 waves (4Mx2N, 64x64 per wave). Flat 72KB smem:
// As = smem[0..49151] (3 bufs x 16K), Bs = smem[49152..73727] (3 x 8K).
// LDS rows 64 B (4x16B slots); slot swizzle phys = log ^ ((row>>1)&3).
// Per K-step t: frag ds_reads from buf[t%3]; issue stage(t+2) [A loads
// NT so B stays L2-resident]; setprio(1) 16 MFMA setprio(0); vmcnt(3);
// ONE s_barrier. Epilogue: C staged in smem then nontemporal coalesced
// stores. Bijective XCD swizzle (m204). AMODE 0: A dense [M][K].
// AMODE 1: A is qkv [M][3456], col k at phys (k>>7)*192+64+(k&127).
template <bool OBF, int AMODE>
__launch_bounds__(512, 2)
__global__ void k_gemm(const u16* __restrict__ A, const u16* __restrict__ Bt,
                       const float* __restrict__ bias, void* __restrict__ C,
                       int K, int nvalid) {
  __shared__ char smem[73728];
  char* AsB0 = smem;            // 3 x 16384
  char* BsB0 = smem + 49152;    // 3 x 8192
  const int tid = threadIdx.x, lane = tid & 63, w = tid >> 6;
  const int wr = w >> 1, wc = w & 1;  // 4M x 2N wave grid
  const int l15 = lane & 15, g = lane >> 4;
  // XCD swizzle
  const int nwg = gridDim.x * gridDim.y;
  int wgid = blockIdx.x + gridDim.x * blockIdx.y;
  int xcd = wgid & 7, local = wgid >> 3;
  int nq = nwg >> 3, rr = nwg & 7;
  int id2 = ((xcd < rr) ? xcd * (nq + 1) : rr * (nq + 1) + (xcd - rr) * nq) + local;
  const size_t m0 = (size_t)(id2 / gridDim.x) * 256;
  const size_t n0 = (size_t)(id2 % gridDim.x) * 128;
  const int Kb = K * 2;                        // B row stride (bytes)
  const int KbA = (AMODE == 0) ? K * 2 : 6912; // A row stride (bytes)
  const char* Ab = (const char*)A + m0 * KbA;
  const char* Bb = (const char*)Bt + n0 * Kb;
  f32x4 acc[4][4] = {};

  auto stage = [&](int buf, int kt) {
    const int abase = (AMODE == 0) ? kt * 2 : ((kt >> 7) * 384 + 128 + ((kt & 127) << 1));
#pragma unroll
    for (int j = 0; j < 2; ++j) {
      int c = j * 512 + tid;                  // A: 1024 chunks of 16B
      int r = c >> 2, sp = c & 3;
      int sl = sp ^ ((r >> 1) & 3);           // inverse slot swizzle on source
      gload_lds16_nt(Ab + (size_t)r * KbA + abase + sl * 16,
                     AsB0 + buf * 16384 + c * 16);
    }
    {
      int c = tid;                            // B: 512 chunks of 16B
      int r = c >> 2, sp = c & 3;
      int sl = sp ^ ((r >> 1) & 3);
      gload_lds16(Bb + (size_t)r * Kb + kt * 2 + sl * 16,
                  BsB0 + buf * 8192 + c * 16);
    }
  };

  const int NT = K >> 5;  // 18 (gemm1) / 72 (gemm2)
  stage(0, 0);
  stage(1, 32);
  asm volatile("s_waitcnt vmcnt(3)" ::: "memory");  // tile0 landed; tile1 in flight
  __builtin_amdgcn_sched_barrier(0);
  __builtin_amdgcn_s_barrier();

  int br = 0, bs = 2;  // read buffer, stage buffer
  for (int t = 0; t < NT; ++t) {
    const char* AsB = AsB0 + br * 16384;
    const char* BsB = BsB0 + br * 8192;
    s16x8 af[4], bfr[4];
#pragma unroll
    for (int i = 0; i < 4; ++i) {
      int ra = wr * 64 + i * 16 + l15;
      af[i] = *(const s16x8*)(AsB + ra * 64 + ((g ^ ((ra >> 1) & 3)) << 4));
      int rb = wc * 64 + i * 16 + l15;
      bfr[i] = *(const s16x8*)(BsB + rb * 64 + ((g ^ ((rb >> 1) & 3)) << 4));
    }
    // stage(t+2) into buf[(t+2)%3]: last read at step t-1; all waves have
    // passed the end-of-(t-1) barrier -> safe without a pre-stage barrier.
    if (t + 2 < NT) stage(bs, (t + 2) * 32);
    __builtin_amdgcn_s_setprio(1);
#pragma unroll
    for (int mi = 0; mi < 4; ++mi)
#pragma unroll
      for (int ni = 0; ni < 4; ++ni)
        acc[mi][ni] = __builtin_amdgcn_mfma_f32_16x16x32_bf16(af[mi], bfr[ni], acc[mi][ni], 0, 0, 0);
    __builtin_amdgcn_s_setprio(0);
    if (t + 1 < NT) {
      if (t + 2 < NT) {
        asm volatile("s_waitcnt vmcnt(3)" ::: "memory");  // stage(t+1) landed
      } else {
        asm volatile("s_waitcnt vmcnt(0)" ::: "memory");  // tail drain
      }
      __builtin_amdgcn_sched_barrier(0);
      __builtin_amdgcn_s_barrier();      // single barrier per K-step
    }
    br = (br == 2) ? 0 : br + 1;
    bs = (bs == 2) ? 0 : bs + 1;
  }

  // ---- epilogue: stage C tile in smem, then nontemporal coalesced stores ----
  __syncthreads();  // all frag reads done; smem reusable
  if (OBF) {
    // gemm1: exact tiling (3456 = 27*128, 25088 = 98*256) -> no guards.
    u16* Cs = (u16*)smem;  // [256][128], 64 KB
#pragma unroll
    for (int ni = 0; ni < 4; ++ni) {
      int n_loc = wc * 64 + ni * 16 + l15;
      float bv = bias[n0 + n_loc];
#pragma unroll
      for (int mi = 0; mi < 4; ++mi) {
        int m_base = wr * 64 + mi * 16 + g * 4;
#pragma unroll
        for (int r = 0; r < 4; ++r)
          Cs[(m_base + r) * 128 + n_loc] = f2bf(acc[mi][ni][r] + bv);
      }
    }
    __syncthreads();
    u16* Cg = (u16*)C + m0 * (size_t)nvalid + n0;
#pragma unroll
    for (int i = 0; i < 8; ++i) {
      int c = i * 512 + tid;
      int row = c >> 4, col8 = (c & 15) * 8;  // 8 u16 = 16 B
      s16x8 v = *(const s16x8*)(Cs + row * 128 + col8);
      __builtin_nontemporal_store(v, (s16x8*)(Cg + (size_t)row * nvalid + col8));
    }
  } else {
    // gemm2: fp32 out, two 64KB half-tiles (wc half h), n<nvalid guards.
    float* Cs = (float*)smem;  // [256][64], 64 KB
#pragma unroll
    for (int h = 0; h < 2; ++h) {
      if (wc == h) {
#pragma unroll
        for (int ni = 0; ni < 4; ++ni) {
          int n_loc = ni * 16 + l15;               // 0..63
          int n_glob = (int)n0 + h * 64 + n_loc;
          float bv = (n_glob < nvalid) ? bias[n_glob] : 0.f;
#pragma unroll
          for (int mi = 0; mi < 4; ++mi) {
            int m_base = wr * 64 + mi * 16 + g * 4;
#pragma unroll
            for (int r = 0; r < 4; ++r)
              Cs[(m_base + r) * 64 + n_loc] = acc[mi][ni][r] + bv;
          }
        }
      }
      __syncthreads();
#pragma unroll
      for (int i = 0; i < 8; ++i) {
        int c = i * 512 + tid;
        int row = c >> 4, col4 = (c & 15) * 4;  // 4 f32 = 16 B
        int n_glob = (int)n0 + h * 64 + col4;
        if (n_glob < nvalid) {
          f32x4 v = *(const f32x4*)(Cs + row * 64 + col4);
          __builtin_nontemporal_store(v, (f32x4*)((float*)C + (size_t)(m0 + row) * nvalid + n_glob));
        }
      }
      if (h == 0) __syncthreads();
    }
  }
}

// ---------------- attention: one block per (b,h), 7 waves ----------------
// qkv [B*196][3456]: per head h: Q at h*192, K at +32, V at +64 (128 wide)
// S^T trick: mfma(K,Q) -> lane owns q-col = qt*16 + (lane&15)
// Wave w computes q-tiles {w, w+7} interleaved (2x ILP); kf/vf LDS loads
// shared. V chunked layout: element (m,d) at
//   ((d>>4)*7+(m>>5))*512 + ((d&15)*4+((m>>3)&3))*8 + (m&7)
// -> PV ds_read_b128 (per dt,kk) is lane-contiguous 1024B: conflict-free.
// Output overwrites the V slot in place. NO-MAX softmax (R9).
__launch_bounds__(448, 2)
__global__ void k_attn(u16* __restrict__ qkv, const float* __restrict__ biasf) {
  __shared__ u16 Vl[8 * 7 * 512];  // 57344 B
  __shared__ u16 Kl[13 * 64 * 8];  // 13312 B
  const int h = blockIdx.x, b = blockIdx.y;
  const int tid = threadIdx.x, lane = tid & 63, w = tid >> 6;  // w: 0..6
  const int g = lane >> 4, q16 = lane & 15;
  const size_t tok0 = (size_t)b * 196;
  u16* qkvb = qkv + tok0 * 3456 + (size_t)h * 192;

  // stage K via gload_lds: 832 chunks; chunks 0..447 one per thread,
  // chunks 448..831 on waves 0..5 (wave-aligned split, uniform LDS base).
  {
    int c = tid;
    int tok = min((c >> 6) * 16 + (c & 15), 195);
    gload_lds16(qkvb + (size_t)tok * 3456 + 32 + ((c >> 4) & 3) * 8,
                (char*)Kl + (size_t)(w * 64) * 16);
    if (tid < 384) {
      int c2 = 448 + tid;
      int tok2 = min((c2 >> 6) * 16 + (c2 & 15), 195);
      gload_lds16(qkvb + (size_t)tok2 * 3456 + 32 + ((c2 >> 4) & 3) * 8,
                  (char*)Kl + (size_t)(448 + w * 64) * 16);
    }
  }
  // stage V: lane (l15,g2): m = mb*16+l15, d8 = db*4+g2 (coalesced 64B
  // global segs); 56 jobs / 7 waves = 8 per wave. Chunked LDS writes.
  {
    int l15 = lane & 15, g2 = lane >> 4;
    for (int j = w; j < 56; j += 7) {
      int db = j / 14, mb = j % 14;
      int m = mb * 16 + l15, d8 = db * 4 + g2;
      int mc = min(m, 195);
      s16x8 v = *(const s16x8*)(qkvb + (size_t)mc * 3456 + 64 + d8 * 8);
      int kk = m >> 5, s2 = (m >> 3) & 3, e7 = m & 7;
      int dtb = d8 >> 1, q8 = (d8 & 1) * 8;
      u16* base = Vl + (((size_t)dtb * 7 + kk) << 9) + s2 * 8 + e7;
#pragma unroll
      for (int e = 0; e < 8; ++e)
        base[(q8 + e) * 32] = (u16)v[e];
    }
  }
  __syncthreads();

  const float scale = 0.17677669529663687f * 1.4426950408889634f;  // /sqrt(32)*log2e
  const int qt0 = w;
  const bool t1v = (w + 7) < 13;          // wave-uniform
  const int qt1 = t1v ? (w + 7) : 12;     // clamped for addresses
  int q0 = qt0 * 16 + q16, q1 = qt1 * 16 + q16;
  s16x8 qf0 = *(const s16x8*)(qkvb + (size_t)min(q0, 195) * 3456 + g * 8);
  s16x8 qf1 = *(const s16x8*)(qkvb + (size_t)min(q1, 195) * 3456 + g * 8);
  const float* bq0 = biasf + (((size_t)(h * 13 + qt0) * 13) << 8) + (q16 << 4) + (g << 2);
  const float* bq1 = biasf + (((size_t)(h * 13 + qt1) * 13) << 8) + (q16 << 4) + (g << 2);
  f32x4 acc0[8] = {}, acc1[8] = {};
  float sum0 = 0.f, sum1 = 0.f;
  const int L1 = ((g & 1) << 5) + q16;  // source lanes holding our q column
  const int L2 = L1 + 16;
  const bool hiSel = (g >> 1) != 0;

#pragma unroll
  for (int kk = 0; kk < 7; ++kk) {
    const bool hasB = (2 * kk + 1) < 13;
    s16x8 kfA = *(const s16x8*)(Kl + ((size_t)(2 * kk) * 64 + lane) * 8);
    s16x8 kfB = {};
    if (hasB) kfB = *(const s16x8*)(Kl + ((size_t)(2 * kk + 1) * 64 + lane) * 8);
    u32 pw[2][4];  // [tile][word]
#pragma unroll
    for (int tl = 0; tl < 2; ++tl) {
      const s16x8 qf = tl ? qf1 : qf0;
      const float* bq = tl ? bq1 : bq0;
      float lsum = 0.f;
      u32 a0, a1, b0 = 0u, b1 = 0u;
      {
        f32x4 z = {};
        f32x4 t = __builtin_amdgcn_mfma_f32_16x16x32_bf16(kfA, qf, z, 0, 0, 0);
        f32x4 b4 = *(const f32x4*)(bq + (2 * kk) * 256);
        float e0 = exp2_fast(t[0] * scale + b4[0]);
        float e1 = exp2_fast(t[1] * scale + b4[1]);
        float e2 = exp2_fast(t[2] * scale + b4[2]);
        float e3 = exp2_fast(t[3] * scale + b4[3]);
        lsum += (e0 + e1) + (e2 + e3);
        a0 = cvtpk_bf16(e0, e1);
        a1 = cvtpk_bf16(e2, e3);
      }
      if (hasB) {
        f32x4 z = {};
        f32x4 t = __builtin_amdgcn_mfma_f32_16x16x32_bf16(kfB, qf, z, 0, 0, 0);
        f32x4 b4 = *(const f32x4*)(bq + (2 * kk + 1) * 256);
        float e0 = exp2_fast(t[0] * scale + b4[0]);
        float e1 = exp2_fast(t[1] * scale + b4[1]);
        float e2 = exp2_fast(t[2] * scale + b4[2]);
        float e3 = exp2_fast(t[3] * scale + b4[3]);
        lsum += (e0 + e1) + (e2 + e3);
        b0 = cvtpk_bf16(e0, e1);
        b1 = cvtpk_bf16(e2, e3);
      }
      if (tl) sum1 += lsum; else sum0 += lsum;
      u32 rA0 = __shfl((int)a0, L1, 64), rA1 = __shfl((int)a1, L1, 64);
      u32 rA2 = __shfl((int)a0, L2, 64), rA3 = __shfl((int)a1, L2, 64);
      u32 rB0 = __shfl((int)b0, L1, 64), rB1 = __shfl((int)b1, L1, 64);
      u32 rB2 = __shfl((int)b0, L2, 64), rB3 = __shfl((int)b1, L2, 64);
      pw[tl][0] = hiSel ? rB0 : rA0;
      pw[tl][1] = hiSel ? rB1 : rA1;
      pw[tl][2] = hiSel ? rB2 : rA2;
      pw[tl][3] = hiSel ? rB3 : rA3;
    }
    union {
      u32 u[4];
      s16x8 v;
    } pa0, pa1;
    pa0.u[0] = pw[0][0]; pa0.u[1] = pw[0][1]; pa0.u[2] = pw[0][2]; pa0.u[3] = pw[0][3];
    pa1.u[0] = pw[1][0]; pa1.u[1] = pw[1][1]; pa1.u[2] = pw[1][2]; pa1.u[3] = pw[1][3];
    __builtin_amdgcn_s_setprio(1);
#pragma unroll
    for (int dt = 0; dt < 8; ++dt) {
      s16x8 vf = *(const s16x8*)(Vl + (((size_t)dt * 7 + kk) << 9) + (((q16 << 2) + g) << 3));
      acc0[dt] = __builtin_amdgcn_mfma_f32_16x16x32_bf16(pa0.v, vf, acc0[dt], 0, 0, 0);
      acc1[dt] = __builtin_amdgcn_mfma_f32_16x16x32_bf16(pa1.v, vf, acc1[dt], 0, 0, 0);
    }
    __builtin_amdgcn_s_setprio(0);
  }

  // epilogue per tile
  sum0 += __shfl_xor(sum0, 16, 64);
  sum0 += __shfl_xor(sum0, 32, 64);
  sum1 += __shfl_xor(sum1, 16, 64);
  sum1 += __shfl_xor(sum1, 32, 64);
  float inv0[4], inv1[4];
#pragma unroll
  for (int r = 0; r < 4; ++r) {
    inv0[r] = 1.f / __shfl(sum0, g * 4 + r, 64);
    inv1[r] = 1.f / __shfl(sum1, g * 4 + r, 64);
  }
#pragma unroll
  for (int dp = 0; dp < 4; ++dp) {
#pragma unroll
    for (int r = 0; r < 4; ++r) {
      int qq0 = qt0 * 16 + g * 4 + r;
      if (qq0 < 196) {
        u32 pk = cvtpk_bf16(acc0[2 * dp][r] * inv0[r], acc0[2 * dp + 1][r] * inv0[r]);
        u16* op = qkvb + (size_t)qq0 * 3456 + 64 + dp * 32 + q16;
        op[0] = (u16)pk;
        op[16] = (u16)(pk >> 16);
      }
      if (t1v) {
        int qq1 = qt1 * 16 + g * 4 + r;
        if (qq1 < 196) {
          u32 pk = cvtpk_bf16(acc1[2 * dp][r] * inv1[r], acc1[2 * dp + 1][r] * inv1[r]);
          u16* op = qkvb + (size_t)qq1 * 3456 + 64 + dp * 32 + q16;
          op[0] = (u16)pk;
          op[16] = (u16)(pk >> 16);
        }
      }
    }
  }
}

// ---------------- launch ----------------
extern "C" void kernel_launch(void* const* d_in, const int* in_sizes, int n_in,
                              void* d_out, int out_size, void* d_ws, size_t ws_size,
                              hipStream_t stream) {
  const float* x = (const float*)d_in[0];
  const float* ln_g = (const float*)d_in[1];
  const float* ln_b = (const float*)d_in[2];
  const float* qkv_w = (const float*)d_in[3];
  const float* qkv_b = (const float*)d_in[4];
  const float* proj_w = (const float*)d_in[5];
  const float* proj_b = (const float*)d_in[6];
  const float* attnb = (const float*)d_in[7];
  const int* idxs = (const int*)d_in[8];
  const int noff = in_sizes[7] / 18;

  char* ws = (char*)d_ws;
  u16* qkv = (u16*)(ws);                   // 25088*3456*2  = 173,408,256
  u16* wq = (u16*)(ws + 173408256);        // 3456*576*2    = 3,981,312
  u16* wp = (u16*)(ws + 177389568);        // 640*2304*2    = 2,949,120
  float* bfull = (float*)(ws + 180338688); // 18*13*13*256*4 = 3,115,008
  const size_t need = 183453696;
  if (ws_size < need) return;

  u16* xn = (u16*)d_out;  // 28.9 MB bf16, fits in 57.8 MB f32 out; dead before proj gemm
  float* out = (float*)d_out;

  k_prep_ln<<<6272 + 16578, 256, 0, stream>>>(x, ln_g, ln_b, xn, qkv_w, proj_w,
                                              attnb, idxs, wq, wp, bfull, noff);
  k_gemm<true, 0><<<dim3(27, 98), 512, 0, stream>>>(xn, wq, qkv_b, qkv, 576, 3456);
  k_attn<<<dim3(18, 128), 448, 0, stream>>>(qkv, bfull);
  k_gemm<false, 1><<<dim3(5, 98), 512, 0, stream>>>(qkv, wp, proj_b, out, 2304, 576);
}

// Round 23
// 320.337 us; speedup vs baseline: 1.3873x; 1.3873x over previous
//
#include <hip/hip_runtime.h>
#include <hip/hip_bf16.h>
#include <cstdint>

// LeViT attention block: LN -> QKV gemm -> biased attention -> proj gemm
// B=128, N=196, DIM=576, H=18, KD=32, DV=128, DH=2304, QKVO=3456
// fp32 in/out; internal compute bf16 MFMA + fp32 accum.
// ws: qkv(173.4M) + wq(4M) + wp(3M) + bias_t(3.1M) = 183.5 MB.
// xn staged in d_out (dead before proj gemm). Attn output overwrites the
// V slot of qkv in place. Bias pre-scaled by log2(e) (exp2-domain softmax).
// GEMM: 256x128 tile, 512 thr (8 waves, 4Mx2N), BK=32, TRIPLE-buffered
// 72 KB LDS at stage-distance 2, ONE barrier per K-step, counted vmcnt(3),
// LDS-staged coalesced C epilogue + T5 setprio.
// R23: REVERT of R21/22 NT experiment (refuted: A panels ARE L2-reused by
// same-row blocks on one XCD — the swizzle's whole point; NT hint forced
// A to HBM latency, MfmaUtil 35->23%, gemm 126->182us).
// Attn: 448 thr / 7 waves, tiles {w,w+7} interleaved (2x ILP); V in
// conflict-free 16B-chunk layout; NO-MAX softmax; prep+LN fused.

typedef uint32_t u32;
typedef unsigned short u16;
using f32x4 = __attribute__((ext_vector_type(4))) float;
using s16x8 = __attribute__((ext_vector_type(8))) short;

#define DEVFN static __device__ __forceinline__

DEVFN u16 f2bf(float f) {  // RNE float->bf16
  u32 u = __builtin_bit_cast(u32, f);
  u = (u + 0x7fffu + ((u >> 16) & 1u)) >> 16;
  return (u16)u;
}

DEVFN u32 cvtpk_bf16(float lo, float hi) {  // packed RNE pair
  u32 r;
  asm("v_cvt_pk_bf16_f32 %0, %1, %2" : "=v"(r) : "v"(lo), "v"(hi));
  return r;
}

DEVFN float exp2_fast(float x) {
  float r;
  asm("v_exp_f32 %0, %1" : "=v"(r) : "v"(x));
  return r;
}

DEVFN void gload_lds16(const void* g, void* l) {
  typedef const __attribute__((address_space(1))) uint32_t* gp_t;
  typedef __attribute__((address_space(3))) uint32_t* lp_t;
  __builtin_amdgcn_global_load_lds((gp_t)g, (lp_t)l, 16, 0, 0);
}

// ---------------- fused LN + prep (cvt wq, cvt_pad wp, bias table) ----------------
// blocks 0..6271: LayerNorm (4 tokens/block); 6272..: prep work.
__launch_bounds__(256)
__global__ void k_prep_ln(const float* __restrict__ x, const float* __restrict__ ln_g,
                          const float* __restrict__ ln_b, u16* __restrict__ xn,
                          const float* __restrict__ qkv_w, const float* __restrict__ proj_w,
                          const float* __restrict__ biases, const int* __restrict__ idxs,
                          u16* __restrict__ wq, u16* __restrict__ wp,
                          float* __restrict__ bfull, int noff) {
  int bid = blockIdx.x;
  if (bid < 6272) {
    int t = bid * 4 + (threadIdx.x >> 6);
    int l = threadIdx.x & 63;
    const float* xt = x + (size_t)t * 576;
    const float4* x4 = (const float4*)xt;
    float4 v0 = x4[l], v1 = x4[64 + l];
    float v2 = xt[512 + l];
    float s = v0.x + v0.y + v0.z + v0.w + v1.x + v1.y + v1.z + v1.w + v2;
    float q = v0.x * v0.x + v0.y * v0.y + v0.z * v0.z + v0.w * v0.w +
              v1.x * v1.x + v1.y * v1.y + v1.z * v1.z + v1.w * v1.w + v2 * v2;
    for (int o = 1; o < 64; o <<= 1) {
      s += __shfl_xor(s, o, 64);
      q += __shfl_xor(q, o, 64);
    }
    float mean = s * (1.f / 576.f);
    float var = q * (1.f / 576.f) - mean * mean;
    float rstd = rsqrtf(var + 1e-5f);
    const float4* g4 = (const float4*)ln_g;
    const float4* b4 = (const float4*)ln_b;
    float4 ga = g4[l], gb = g4[64 + l];
    float4 ba = b4[l], bb = b4[64 + l];
    float gc = ln_g[512 + l], bc = ln_b[512 + l];
    u16* ot = xn + (size_t)t * 576;
    ushort4 o0, o1;
    o0.x = f2bf((v0.x - mean) * rstd * ga.x + ba.x);
    o0.y = f2bf((v0.y - mean) * rstd * ga.y + ba.y);
    o0.z = f2bf((v0.z - mean) * rstd * ga.z + ba.z);
    o0.w = f2bf((v0.w - mean) * rstd * ga.w + ba.w);
    o1.x = f2bf((v1.x - mean) * rstd * gb.x + bb.x);
    o1.y = f2bf((v1.y - mean) * rstd * gb.y + bb.y);
    o1.z = f2bf((v1.z - mean) * rstd * gb.z + bb.z);
    o1.w = f2bf((v1.w - mean) * rstd * gb.w + bb.w);
    ((ushort4*)ot)[l] = o0;
    ((ushort4*)ot)[64 + l] = o1;
    ot[512 + l] = f2bf((v2 - mean) * rstd * gc + bc);
  } else if (bid < 6272 + 7776) {
    int i = (bid - 6272) * 256 + threadIdx.x;
    if (i < 1990656) wq[i] = f2bf(qkv_w[i]);
  } else if (bid < 6272 + 7776 + 5760) {
    int i = (bid - 6272 - 7776) * 256 + threadIdx.x;  // over 640*2304
    int r = i / 2304, c = i % 2304;
    wp[i] = (r < 576) ? f2bf(proj_w[r * 2304 + c]) : (u16)0;
  } else {
    int i = (bid - 6272 - 7776 - 5760) * 256 + threadIdx.x;  // over 18*13*13*256
    int r = i & 3, g = (i >> 2) & 3, q16 = (i >> 4) & 15;
    int t = i >> 8;
    int mt = t % 13, t2 = t / 13;
    int qt = t2 % 13, h = t2 / 13;
    int q = qt * 16 + q16, m = mt * 16 + g * 4 + r;
    float v = -1e30f;
    if (q < 196 && m < 196)
      v = biases[h * noff + idxs[q * 196 + m]] * 1.4426950408889634f;
    bfull[i] = v;
  }
}

// ---------------- GEMM: C[M,nvalid] = A[M,K] * Bt[N,K]^T + bias ----------------
// 256x128 tile, BK=32, 8 waves (4Mx2N, 64x64 per wave). Flat 72KB smem:
// As = smem[0..49151] (3 bufs x 16K), Bs = smem[49152..73727] (3 x 8K).
// LDS rows 64 B (4x16B slots); slot swizzle phys = log ^ ((row>>1)&3).
// Per K-step t: frag ds_reads from buf[t%3]; issue stage(t+2); setprio(1)
// 16 MFMA setprio(0); vmcnt(3); ONE s_barrier. Epilogue: C staged in smem
// then coalesced 16B/lane stores. Bijective XCD swizzle (m204).
// AMODE 0: A dense [M][K]. AMODE 1: A is qkv [M][3456], col k at phys
// (k>>7)*192 + 64 + (k&127).
template <bool OBF, int AMODE>
__launch_bounds__(512, 2)
__global__ void k_gemm(const u16* __restrict__ A, const u16* __restrict__ Bt,
                       const float* __restrict__ bias, void* __restrict__ C,
                       int K, int nvalid) {
  __shared__ char smem[73728];
  char* AsB0 = smem;            // 3 x 16384
  char* BsB0 = smem + 49152;    // 3 x 8192
  const int tid = threadIdx.x, lane = tid & 63, w = tid >> 6;
  const int wr = w >> 1, wc = w & 1;  // 4M x 2N wave grid
  const int l15 = lane & 15, g = lane >> 4;
  // XCD swizzle
  const int nwg = gridDim.x * gridDim.y;
  int wgid = blockIdx.x + gridDim.x * blockIdx.y;
  int xcd = wgid & 7, local = wgid >> 3;
  int nq = nwg >> 3, rr = nwg & 7;
  int id2 = ((xcd < rr) ? xcd * (nq + 1) : rr * (nq + 1) + (xcd - rr) * nq) + local;
  const size_t m0 = (size_t)(id2 / gridDim.x) * 256;
  const size_t n0 = (size_t)(id2 % gridDim.x) * 128;
  const int Kb = K * 2;                        // B row stride (bytes)
  const int KbA = (AMODE == 0) ? K * 2 : 6912; // A row stride (bytes)
  const char* Ab = (const char*)A + m0 * KbA;
  const char* Bb = (const char*)Bt + n0 * Kb;
  f32x4 acc[4][4] = {};

  auto stage = [&](int buf, int kt) {
    const int abase = (AMODE == 0) ? kt * 2 : ((kt >> 7) * 384 + 128 + ((kt & 127) << 1));
#pragma unroll
    for (int j = 0; j < 2; ++j) {
      int c = j * 512 + tid;                  // A: 1024 chunks of 16B
      int r = c >> 2, sp = c & 3;
      int sl = sp ^ ((r >> 1) & 3);           // inverse slot swizzle on source
      gload_lds16(Ab + (size_t)r * KbA + abase + sl * 16,
                  AsB0 + buf * 16384 + c * 16);
    }
    {
      int c = tid;                            // B: 512 chunks of 16B
      int r = c >> 2, sp = c & 3;
      int sl = sp ^ ((r >> 1) & 3);
      gload_lds16(Bb + (size_t)r * Kb + kt * 2 + sl * 16,
                  BsB0 + buf * 8192 + c * 16);
    }
  };

  const int NT = K >> 5;  // 18 (gemm1) / 72 (gemm2)
  stage(0, 0);
  stage(1, 32);
  asm volatile("s_waitcnt vmcnt(3)" ::: "memory");  // tile0 landed; tile1 in flight
  __builtin_amdgcn_sched_barrier(0);
  __builtin_amdgcn_s_barrier();

  int br = 0, bs = 2;  // read buffer, stage buffer
  for (int t = 0; t < NT; ++t) {
    const char* AsB = AsB0 + br * 16384;
    const char* BsB = BsB0 + br * 8192;
    s16x8 af[4], bfr[4];
#pragma unroll
    for (int i = 0; i < 4; ++i) {
      int ra = wr * 64 + i * 16 + l15;
      af[i] = *(const s16x8*)(AsB + ra * 64 + ((g ^ ((ra >> 1) & 3)) << 4));
      int rb = wc * 64 + i * 16 + l15;
      bfr[i] = *(const s16x8*)(BsB + rb * 64 + ((g ^ ((rb >> 1) & 3)) << 4));
    }
    // stage(t+2) into buf[(t+2)%3]: last read at step t-1; all waves have
    // passed the end-of-(t-1) barrier -> safe without a pre-stage barrier.
    if (t + 2 < NT) stage(bs, (t + 2) * 32);
    __builtin_amdgcn_s_setprio(1);
#pragma unroll
    for (int mi = 0; mi < 4; ++mi)
#pragma unroll
      for (int ni = 0; ni < 4; ++ni)
        acc[mi][ni] = __builtin_amdgcn_mfma_f32_16x16x32_bf16(af[mi], bfr[ni], acc[mi][ni], 0, 0, 0);
    __builtin_amdgcn_s_setprio(0);
    if (t + 1 < NT) {
      if (t + 2 < NT) {
        asm volatile("s_waitcnt vmcnt(3)" ::: "memory");  // stage(t+1) landed
      } else {
        asm volatile("s_waitcnt vmcnt(0)" ::: "memory");  // tail drain
      }
      __builtin_amdgcn_sched_barrier(0);
      __builtin_amdgcn_s_barrier();      // single barrier per K-step
    }
    br = (br == 2) ? 0 : br + 1;
    bs = (bs == 2) ? 0 : bs + 1;
  }

  // ---- epilogue: stage C tile in smem, then coalesced stores ----
  __syncthreads();  // all frag reads done; smem reusable
  if (OBF) {
    // gemm1: exact tiling (3456 = 27*128, 25088 = 98*256) -> no guards.
    u16* Cs = (u16*)smem;  // [256][128], 64 KB
#pragma unroll
    for (int ni = 0; ni < 4; ++ni) {
      int n_loc = wc * 64 + ni * 16 + l15;
      float bv = bias[n0 + n_loc];
#pragma unroll
      for (int mi = 0; mi < 4; ++mi) {
        int m_base = wr * 64 + mi * 16 + g * 4;
#pragma unroll
        for (int r = 0; r < 4; ++r)
          Cs[(m_base + r) * 128 + n_loc] = f2bf(acc[mi][ni][r] + bv);
      }
    }
    __syncthreads();
    u16* Cg = (u16*)C + m0 * (size_t)nvalid + n0;
#pragma unroll
    for (int i = 0; i < 8; ++i) {
      int c = i * 512 + tid;
      int row = c >> 4, col8 = (c & 15) * 8;  // 8 u16 = 16 B
      s16x8 v = *(const s16x8*)(Cs + row * 128 + col8);
      *(s16x8*)(Cg + (size_t)row * nvalid + col8) = v;
    }
  } else {
    // gemm2: fp32 out, two 64KB half-tiles (wc half h), n<nvalid guards.
    float* Cs = (float*)smem;  // [256][64], 64 KB
#pragma unroll
    for (int h = 0; h < 2; ++h) {
      if (wc == h) {
#pragma unroll
        for (int ni = 0; ni < 4; ++ni) {
          int n_loc = ni * 16 + l15;               // 0..63
          int n_glob = (int)n0 + h * 64 + n_loc;
          float bv = (n_glob < nvalid) ? bias[n_glob] : 0.f;
#pragma unroll
          for (int mi = 0; mi < 4; ++mi) {
            int m_base = wr * 64 + mi * 16 + g * 4;
#pragma unroll
            for (int r = 0; r < 4; ++r)
              Cs[(m_base + r) * 64 + n_loc] = acc[mi][ni][r] + bv;
          }
        }
      }
      __syncthreads();
#pragma unroll
      for (int i = 0; i < 8; ++i) {
        int c = i * 512 + tid;
        int row = c >> 4, col4 = (c & 15) * 4;  // 4 f32 = 16 B
        int n_glob = (int)n0 + h * 64 + col4;
        if (n_glob < nvalid) {
          float4 v = *(const float4*)(Cs + row * 64 + col4);
          *(float4*)((float*)C + (size_t)(m0 + row) * nvalid + n_glob) = v;
        }
      }
      if (h == 0) __syncthreads();
    }
  }
}

// ---------------- attention: one block per (b,h), 7 waves ----------------
// qkv [B*196][3456]: per head h: Q at h*192, K at +32, V at +64 (128 wide)
// S^T trick: mfma(K,Q) -> lane owns q-col = qt*16 + (lane&15)
// Wave w computes q-tiles {w, w+7} interleaved (2x ILP); kf/vf LDS loads
// shared. V chunked layout: element (m,d) at
//   ((d>>4)*7+(m>>5))*512 + ((d&15)*4+((m>>3)&3))*8 + (m&7)
// -> PV ds_read_b128 (per dt,kk) is lane-contiguous 1024B: conflict-free.
// Output overwrites the V slot in place. NO-MAX softmax (R9).
__launch_bounds__(448, 2)
__global__ void k_attn(u16* __restrict__ qkv, const float* __restrict__ biasf) {
  __shared__ u16 Vl[8 * 7 * 512];  // 57344 B
  __shared__ u16 Kl[13 * 64 * 8];  // 13312 B
  const int h = blockIdx.x, b = blockIdx.y;
  const int tid = threadIdx.x, lane = tid & 63, w = tid >> 6;  // w: 0..6
  const int g = lane >> 4, q16 = lane & 15;
  const size_t tok0 = (size_t)b * 196;
  u16* qkvb = qkv + tok0 * 3456 + (size_t)h * 192;

  // stage K via gload_lds: 832 chunks; chunks 0..447 one per thread,
  // chunks 448..831 on waves 0..5 (wave-aligned split, uniform LDS base).
  {
    int c = tid;
    int tok = min((c >> 6) * 16 + (c & 15), 195);
    gload_lds16(qkvb + (size_t)tok * 3456 + 32 + ((c >> 4) & 3) * 8,
                (char*)Kl + (size_t)(w * 64) * 16);
    if (tid < 384) {
      int c2 = 448 + tid;
      int tok2 = min((c2 >> 6) * 16 + (c2 & 15), 195);
      gload_lds16(qkvb + (size_t)tok2 * 3456 + 32 + ((c2 >> 4) & 3) * 8,
                  (char*)Kl + (size_t)(448 + w * 64) * 16);
    }
  }
  // stage V: lane (l15,g2): m = mb*16+l15, d8 = db*4+g2 (coalesced 64B
  // global segs); 56 jobs / 7 waves = 8 per wave. Chunked LDS writes.
  {
    int l15 = lane & 15, g2 = lane >> 4;
    for (int j = w; j < 56; j += 7) {
      int db = j / 14, mb = j % 14;
      int m = mb * 16 + l15, d8 = db * 4 + g2;
      int mc = min(m, 195);
      s16x8 v = *(const s16x8*)(qkvb + (size_t)mc * 3456 + 64 + d8 * 8);
      int kk = m >> 5, s2 = (m >> 3) & 3, e7 = m & 7;
      int dtb = d8 >> 1, q8 = (d8 & 1) * 8;
      u16* base = Vl + (((size_t)dtb * 7 + kk) << 9) + s2 * 8 + e7;
#pragma unroll
      for (int e = 0; e < 8; ++e)
        base[(q8 + e) * 32] = (u16)v[e];
    }
  }
  __syncthreads();

  const float scale = 0.17677669529663687f * 1.4426950408889634f;  // /sqrt(32)*log2e
  const int qt0 = w;
  const bool t1v = (w + 7) < 13;          // wave-uniform
  const int qt1 = t1v ? (w + 7) : 12;     // clamped for addresses
  int q0 = qt0 * 16 + q16, q1 = qt1 * 16 + q16;
  s16x8 qf0 = *(const s16x8*)(qkvb + (size_t)min(q0, 195) * 3456 + g * 8);
  s16x8 qf1 = *(const s16x8*)(qkvb + (size_t)min(q1, 195) * 3456 + g * 8);
  const float* bq0 = biasf + (((size_t)(h * 13 + qt0) * 13) << 8) + (q16 << 4) + (g << 2);
  const float* bq1 = biasf + (((size_t)(h * 13 + qt1) * 13) << 8) + (q16 << 4) + (g << 2);
  f32x4 acc0[8] = {}, acc1[8] = {};
  float sum0 = 0.f, sum1 = 0.f;
  const int L1 = ((g & 1) << 5) + q16;  // source lanes holding our q column
  const int L2 = L1 + 16;
  const bool hiSel = (g >> 1) != 0;

#pragma unroll
  for (int kk = 0; kk < 7; ++kk) {
    const bool hasB = (2 * kk + 1) < 13;
    s16x8 kfA = *(const s16x8*)(Kl + ((size_t)(2 * kk) * 64 + lane) * 8);
    s16x8 kfB = {};
    if (hasB) kfB = *(const s16x8*)(Kl + ((size_t)(2 * kk + 1) * 64 + lane) * 8);
    u32 pw[2][4];  // [tile][word]
#pragma unroll
    for (int tl = 0; tl < 2; ++tl) {
      const s16x8 qf = tl ? qf1 : qf0;
      const float* bq = tl ? bq1 : bq0;
      float lsum = 0.f;
      u32 a0, a1, b0 = 0u, b1 = 0u;
      {
        f32x4 z = {};
        f32x4 t = __builtin_amdgcn_mfma_f32_16x16x32_bf16(kfA, qf, z, 0, 0, 0);
        f32x4 b4 = *(const f32x4*)(bq + (2 * kk) * 256);
        float e0 = exp2_fast(t[0] * scale + b4[0]);
        float e1 = exp2_fast(t[1] * scale + b4[1]);
        float e2 = exp2_fast(t[2] * scale + b4[2]);
        float e3 = exp2_fast(t[3] * scale + b4[3]);
        lsum += (e0 + e1) + (e2 + e3);
        a0 = cvtpk_bf16(e0, e1);
        a1 = cvtpk_bf16(e2, e3);
      }
      if (hasB) {
        f32x4 z = {};
        f32x4 t = __builtin_amdgcn_mfma_f32_16x16x32_bf16(kfB, qf, z, 0, 0, 0);
        f32x4 b4 = *(const f32x4*)(bq + (2 * kk + 1) * 256);
        float e0 = exp2_fast(t[0] * scale + b4[0]);
        float e1 = exp2_fast(t[1] * scale + b4[1]);
        float e2 = exp2_fast(t[2] * scale + b4[2]);
        float e3 = exp2_fast(t[3] * scale + b4[3]);
        lsum += (e0 + e1) + (e2 + e3);
        b0 = cvtpk_bf16(e0, e1);
        b1 = cvtpk_bf16(e2, e3);
      }
      if (tl) sum1 += lsum; else sum0 += lsum;
      u32 rA0 = __shfl((int)a0, L1, 64), rA1 = __shfl((int)a1, L1, 64);
      u32 rA2 = __shfl((int)a0, L2, 64), rA3 = __shfl((int)a1, L2, 64);
      u32 rB0 = __shfl((int)b0, L1, 64), rB1 = __shfl((int)b1, L1, 64);
      u32 rB2 = __shfl((int)b0, L2, 64), rB3 = __shfl((int)b1, L2, 64);
      pw[tl][0] = hiSel ? rB0 : rA0;
      pw[tl][1] = hiSel ? rB1 : rA1;
      pw[tl][2] = hiSel ? rB2 : rA2;
      pw[tl][3] = hiSel ? rB3 : rA3;
    }
    union {
      u32 u[4];
      s16x8 v;
    } pa0, pa1;
    pa0.u[0] = pw[0][0]; pa0.u[1] = pw[0][1]; pa0.u[2] = pw[0][2]; pa0.u[3] = pw[0][3];
    pa1.u[0] = pw[1][0]; pa1.u[1] = pw[1][1]; pa1.u[2] = pw[1][2]; pa1.u[3] = pw[1][3];
    __builtin_amdgcn_s_setprio(1);
#pragma unroll
    for (int dt = 0; dt < 8; ++dt) {
      s16x8 vf = *(const s16x8*)(Vl + (((size_t)dt * 7 + kk) << 9) + (((q16 << 2) + g) << 3));
      acc0[dt] = __builtin_amdgcn_mfma_f32_16x16x32_bf16(pa0.v, vf, acc0[dt], 0, 0, 0);
      acc1[dt] = __builtin_amdgcn_mfma_f32_16x16x32_bf16(pa1.v, vf, acc1[dt], 0, 0, 0);
    }
    __builtin_amdgcn_s_setprio(0);
  }

  // epilogue per tile
  sum0 += __shfl_xor(sum0, 16, 64);
  sum0 += __shfl_xor(sum0, 32, 64);
  sum1 += __shfl_xor(sum1, 16, 64);
  sum1 += __shfl_xor(sum1, 32, 64);
  float inv0[4], inv1[4];
#pragma unroll
  for (int r = 0; r < 4; ++r) {
    inv0[r] = 1.f / __shfl(sum0, g * 4 + r, 64);
    inv1[r] = 1.f / __shfl(sum1, g * 4 + r, 64);
  }
#pragma unroll
  for (int dp = 0; dp < 4; ++dp) {
#pragma unroll
    for (int r = 0; r < 4; ++r) {
      int qq0 = qt0 * 16 + g * 4 + r;
      if (qq0 < 196) {
        u32 pk = cvtpk_bf16(acc0[2 * dp][r] * inv0[r], acc0[2 * dp + 1][r] * inv0[r]);
        u16* op = qkvb + (size_t)qq0 * 3456 + 64 + dp * 32 + q16;
        op[0] = (u16)pk;
        op[16] = (u16)(pk >> 16);
      }
      if (t1v) {
        int qq1 = qt1 * 16 + g * 4 + r;
        if (qq1 < 196) {
          u32 pk = cvtpk_bf16(acc1[2 * dp][r] * inv1[r], acc1[2 * dp + 1][r] * inv1[r]);
          u16* op = qkvb + (size_t)qq1 * 3456 + 64 + dp * 32 + q16;
          op[0] = (u16)pk;
          op[16] = (u16)(pk >> 16);
        }
      }
    }
  }
}

// ---------------- launch ----------------
extern "C" void kernel_launch(void* const* d_in, const int* in_sizes, int n_in,
                              void* d_out, int out_size, void* d_ws, size_t ws_size,
                              hipStream_t stream) {
  const float* x = (const float*)d_in[0];
  const float* ln_g = (const float*)d_in[1];
  const float* ln_b = (const float*)d_in[2];
  const float* qkv_w = (const float*)d_in[3];
  const float* qkv_b = (const float*)d_in[4];
  const float* proj_w = (const float*)d_in[5];
  const float* proj_b = (const float*)d_in[6];
  const float* attnb = (const float*)d_in[7];
  const int* idxs = (const int*)d_in[8];
  const int noff = in_sizes[7] / 18;

  char* ws = (char*)d_ws;
  u16* qkv = (u16*)(ws);                   // 25088*3456*2  = 173,408,256
  u16* wq = (u16*)(ws + 173408256);        // 3456*576*2    = 3,981,312
  u16* wp = (u16*)(ws + 177389568);        // 640*2304*2    = 2,949,120
  float* bfull = (float*)(ws + 180338688); // 18*13*13*256*4 = 3,115,008
  const size_t need = 183453696;
  if (ws_size < need) return;

  u16* xn = (u16*)d_out;  // 28.9 MB bf16, fits in 57.8 MB f32 out; dead before proj gemm
  float* out = (float*)d_out;

  k_prep_ln<<<6272 + 16578, 256, 0, stream>>>(x, ln_g, ln_b, xn, qkv_w, proj_w,
                                              attnb, idxs, wq, wp, bfull, noff);
  k_gemm<true, 0><<<dim3(27, 98), 512, 0, stream>>>(xn, wq, qkv_b, qkv, 576, 3456);
  k_attn<<<dim3(18, 128), 448, 0, stream>>>(qkv, bfull);
  k_gemm<false, 1><<<dim3(5, 98), 512, 0, stream>>>(qkv, wp, proj_b, out, 2304, 576);
}